// Round 4
// baseline (124.036 us; speedup 1.0000x reference)
//
#include <hip/hip_runtime.h>

// DCN CrossLayer: B=16384, F=1024, L=3, fp32.
// Algebraic expansion (verified vs reference across v1-v4):
//   d_j = x0 . w_j (per-row)     t01=b0.w1  t02=b0.w2  t12=b1.w2 (global)
//   a1 = 1+d0;  s1 = a1*d1 + t01;  a2 = a1+s1;  s2 = a2*d2 + t02+t12
//   out = x0*(a2+s2) + (b0+b1+b2)
//
// v5: two-pass split. v4 proved the single-pass kernel is NOT instruction
// bound (40->24 mem inst/row changed nothing, ~36.6us @ ~3.7 TB/s vs the
// 6.5 TB/s the poison fills hit in the same window). Theory: the per-row
// serial chain (load -> dots -> butterfly -> store) phase-convoys the
// machine; reads and writes never stream independently.
//   prep  : t-terms + bias_sum (1 block, ~2us)
//   pass1 : S[row] for all rows — pure read-reduce, no big-store
//           dependency. HBM: 64 MiB read.
//   pass2 : out = x*S + bias_sum — pure elementwise stream (the proven
//           6.3 TB/s copy pattern). x is L3-resident from pass1 (64 MiB
//           << 256 MiB Infinity Cache, back-to-back dispatches), so HBM
//           side is write-only 64 MiB.
// ws layout (floats): [0..2]=t01,t02,t12  [4..1027]=bias_sum  [2048..18431]=S
// No forced __launch_bounds__ min (v3 lesson: forcing 8 waves/SIMD spilled
// x to scratch). All kernels have small live sets (<48 VGPR).

constexpr int B = 16384;
constexpr int F = 1024;      // 256 float4 per row
constexpr int BLOCK = 256;   // 4 waves

// ---------------------------------------------------------------- prep ----
__global__ __launch_bounds__(BLOCK) void prep_kernel(
    const float* __restrict__ kernels,  // [3, F]
    const float* __restrict__ bias,     // [3, F]
    float* __restrict__ ws)
{
    const int tid = threadIdx.x;
    const float4* w1v = (const float4*)(kernels + F);
    const float4* w2v = (const float4*)(kernels + 2 * F);
    const float4* b0v = (const float4*)(bias);
    const float4* b1v = (const float4*)(bias + F);
    const float4* b2v = (const float4*)(bias + 2 * F);

    // bias_sum: thread t owns float4 t (256 threads x float4 = 1024 floats).
    const float4 B0 = b0v[tid];
    const float4 B1 = b1v[tid];
    const float4 B2 = b2v[tid];
    float4 bs;
    bs.x = B0.x + B1.x + B2.x;
    bs.y = B0.y + B1.y + B2.y;
    bs.z = B0.z + B1.z + B2.z;
    bs.w = B0.w + B1.w + B2.w;
    ((float4*)(ws + 4))[tid] = bs;

    // wave 0: the three bias-kernel dots.
    if (tid < 64) {
        float t01 = 0.f, t02 = 0.f, t12 = 0.f;
#pragma unroll
        for (int c = 0; c < 4; ++c) {
            const int i = c * 64 + tid;
            const float4 w1 = w1v[i];
            const float4 w2 = w2v[i];
            const float4 b0 = b0v[i];
            const float4 b1 = b1v[i];
            t01 = fmaf(b0.x, w1.x, t01); t01 = fmaf(b0.y, w1.y, t01);
            t01 = fmaf(b0.z, w1.z, t01); t01 = fmaf(b0.w, w1.w, t01);
            t02 = fmaf(b0.x, w2.x, t02); t02 = fmaf(b0.y, w2.y, t02);
            t02 = fmaf(b0.z, w2.z, t02); t02 = fmaf(b0.w, w2.w, t02);
            t12 = fmaf(b1.x, w2.x, t12); t12 = fmaf(b1.y, w2.y, t12);
            t12 = fmaf(b1.z, w2.z, t12); t12 = fmaf(b1.w, w2.w, t12);
        }
#pragma unroll
        for (int off = 32; off >= 1; off >>= 1) {
            t01 += __shfl_xor(t01, off, 64);
            t02 += __shfl_xor(t02, off, 64);
            t12 += __shfl_xor(t12, off, 64);
        }
        if (tid == 0) { ws[0] = t01; ws[1] = t02; ws[2] = t12; }
    }
}

// --------------------------------------------------------------- pass 1 ----
// One wave per row: d0,d1,d2 -> butterfly -> scalar recurrence -> S[row].
// Read-only on the big stream; retire with a single 4 B store.
__global__ __launch_bounds__(BLOCK) void pass1_kernel(
    const float* __restrict__ x,        // [B, F]
    const float* __restrict__ kernels,  // [3, F]
    float* __restrict__ ws)
{
    const int lane = threadIdx.x & 63;
    const int wave = threadIdx.x >> 6;
    const int row  = blockIdx.x * 4 + wave;

    const float4* xrow = (const float4*)(x + (size_t)row * F);
    const float4* w0v  = (const float4*)(kernels);
    const float4* w1v  = (const float4*)(kernels + F);
    const float4* w2v  = (const float4*)(kernels + 2 * F);

    float d0 = 0.f, d1 = 0.f, d2 = 0.f;
#pragma unroll
    for (int c = 0; c < 4; ++c) {
        const int i = c * 64 + lane;
        const float4 xv = xrow[i];
        const float4 w0 = w0v[i];
        const float4 w1 = w1v[i];
        const float4 w2 = w2v[i];
        d0 = fmaf(xv.x, w0.x, d0); d0 = fmaf(xv.y, w0.y, d0);
        d0 = fmaf(xv.z, w0.z, d0); d0 = fmaf(xv.w, w0.w, d0);
        d1 = fmaf(xv.x, w1.x, d1); d1 = fmaf(xv.y, w1.y, d1);
        d1 = fmaf(xv.z, w1.z, d1); d1 = fmaf(xv.w, w1.w, d1);
        d2 = fmaf(xv.x, w2.x, d2); d2 = fmaf(xv.y, w2.y, d2);
        d2 = fmaf(xv.z, w2.z, d2); d2 = fmaf(xv.w, w2.w, d2);
    }

#pragma unroll
    for (int off = 32; off >= 1; off >>= 1) {
        d0 += __shfl_xor(d0, off, 64);
        d1 += __shfl_xor(d1, off, 64);
        d2 += __shfl_xor(d2, off, 64);
    }

    if (lane == 0) {
        const float t01  = ws[0];
        const float tsum = ws[1] + ws[2];
        const float a1 = 1.f + d0;
        const float s1 = fmaf(a1, d1, t01);
        const float a2 = a1 + s1;
        const float s2 = fmaf(a2, d2, tsum);
        ws[2048 + row] = a2 + s2;   // S
    }
}

// --------------------------------------------------------------- pass 2 ----
// Pure elementwise stream: out = x*S[row] + bias_sum. 8 float4/thread,
// all iterations independent (copy-kernel structure). x reads hit L3.
__global__ __launch_bounds__(BLOCK) void pass2_kernel(
    const float* __restrict__ x,
    const float* __restrict__ ws,
    float* __restrict__ out)
{
    const int tid  = blockIdx.x * BLOCK + threadIdx.x;
    const int wid  = tid >> 6;          // global wave id: covers 512 float4 = 2 rows
    const int lane = tid & 63;

    const float4* xv  = (const float4*)x;
    float4*       ov  = (float4*)out;
    const float4* bsv = (const float4*)(ws + 4);
    const float*  Sp  = ws + 2048;

#pragma unroll
    for (int k = 0; k < 8; ++k) {
        const int i   = wid * 512 + k * 64 + lane;  // float4 index, coalesced
        const int row = i >> 8;                     // wave-uniform per k
        const float  s  = Sp[row];
        const float4 xq = xv[i];
        const float4 bs = bsv[i & 255];
        float4 o;
        o.x = fmaf(xq.x, s, bs.x);
        o.y = fmaf(xq.y, s, bs.y);
        o.z = fmaf(xq.z, s, bs.z);
        o.w = fmaf(xq.w, s, bs.w);
        ov[i] = o;
    }
}

extern "C" void kernel_launch(void* const* d_in, const int* in_sizes, int n_in,
                              void* d_out, int out_size, void* d_ws, size_t ws_size,
                              hipStream_t stream) {
    const float* x       = (const float*)d_in[0];
    const float* kernels = (const float*)d_in[1];
    const float* bias    = (const float*)d_in[2];
    float* out           = (float*)d_out;
    float* ws            = (float*)d_ws;   // needs 18432 floats (72 KiB)

    prep_kernel<<<dim3(1), dim3(BLOCK), 0, stream>>>(kernels, bias, ws);
    pass1_kernel<<<dim3(B / 4), dim3(BLOCK), 0, stream>>>(x, kernels, ws);
    // B*F/4 float4 / (256 thr * 8 f4) = 2048 blocks, zero tail
    pass2_kernel<<<dim3(2048), dim3(BLOCK), 0, stream>>>(x, ws, out);
}